// Round 1
// 591.187 us; speedup vs baseline: 1.1214x; 1.1214x over previous
//
#include <hip/hip_runtime.h>
#include <hip/hip_bf16.h>

#define BB 8
#define LL 1024
#define TT 10
#define TILE 64
#define NTILE (LL/TILE)            // 16
#define NPAIR (NTILE*(NTILE+1)/2)  // 136
#define SPAD 65                    // 64 + 1 pad, conflict-free transpose reads
#define S_CONST 2.1972245773362196f

typedef __hip_bfloat16 bf16;

static __device__ __forceinline__ float sigm(float v) {
    return 1.0f / (1.0f + __expf(-v));
}

// ---- packed (uu, ahat) state: low 16 bits = uu (bf16), high 16 = ahat (bf16) ----
static __device__ __forceinline__ unsigned short f2bf(float v) {
    bf16 h = __float2bfloat16(v);              // RNE, same rounding as before
    unsigned short b; __builtin_memcpy(&b, &h, 2); return b;
}
static __device__ __forceinline__ float lo2f(unsigned int v) {  // exact bf16->f32
    return __uint_as_float(v << 16);
}
static __device__ __forceinline__ float hi2f(unsigned int v) {
    return __uint_as_float(v & 0xffff0000u);
}
static __device__ __forceinline__ unsigned int pk2(float uu, float ah) {
    return (unsigned int)f2bf(uu) | ((unsigned int)f2bf(ah) << 16);
}
// uu already an exact bf16 round-trip value -> bits via shift, no re-round
static __device__ __forceinline__ unsigned int pk_rt(float uu_exact, float ah) {
    return (__float_as_uint(uu_exact) >> 16) | ((unsigned int)f2bf(ah) << 16);
}

static __device__ __forceinline__ void pair_from_idx(int p, int& I, int& J) {
    int i = 0;
    while (p >= NTILE - i) { p -= NTILE - i; i++; }
    I = i; J = i + p;
}

// h = relu(W1 f + b1); out = relu(W2 h + b2).  w: [0..8]=W1 row-major [o][i], [9..11]=b1, [12..14]=W2, [15]=b2
static __device__ __forceinline__ float mlp3(float f0, float f1, float f2, const float* w) {
    float h0 = fmaxf(w[0]*f0 + w[1]*f1 + w[2]*f2 + w[9],  0.0f);
    float h1 = fmaxf(w[3]*f0 + w[4]*f1 + w[5]*f2 + w[10], 0.0f);
    float h2 = fmaxf(w[6]*f0 + w[7]*f1 + w[8]*f2 + w[11], 0.0f);
    return fmaxf(w[12]*h0 + w[13]*h1 + w[14]*h2 + w[15], 0.0f);
}

static __device__ __forceinline__ float ahnew_calc(float ah, float grad, float uuv, const float* w) {
    float va = mlp3(ah, grad, uuv, w);       // a-MLP  (w[0..15])
    float vr = mlp3(ah, grad, uuv, w + 16);  // rho-MLP (w[16..31])
    float v = fmaxf(fabsf(va) - vr, 0.0f);   // relu(|a| - rho); >=0 so clip(-1,1) == min(.,1)
    return fminf(v, 1.0f);
}

// ---- fused prep + rowsum(a0): read u tiles, write packed state, accumulate rs0 ----
__global__ __launch_bounds__(256) void k_init(const float* __restrict__ u,
                                              const float* __restrict__ x,
                                              unsigned int* __restrict__ st,
                                              float* __restrict__ rs0) {
    __shared__ float stA[TILE * SPAD];   // a0 staging for column reduce
    __shared__ float stB[TILE * SPAD];   // ahat_JI
    __shared__ float xI[4 * TILE], xJ[4 * TILE];
    __shared__ float rsI[TILE], rsJ[TILE];

    int b = blockIdx.x / NPAIR, p = blockIdx.x % NPAIR;
    int I, J; pair_from_idx(p, I, J);
    int Ib = I * TILE, Jb = J * TILE;
    bool diag = (I == J);
    int tid = threadIdx.x, c = tid & 63, rg = tid >> 6;

    { int row = tid >> 2, k2 = tid & 3;
      xI[k2*TILE + row] = x[((size_t)b*LL + Ib + row)*4 + k2];
      xJ[k2*TILE + row] = x[((size_t)b*LL + Jb + row)*4 + k2]; }
    if (tid < TILE) { rsI[tid] = 0.0f; rsJ[tid] = 0.0f; }

    float ahv[16];
    size_t baseIJ = ((size_t)b*LL + Ib)*LL + Jb;
    #pragma unroll
    for (int k = 0; k < 16; k++) {
        size_t idx = baseIJ + (size_t)(rg + 4*k)*LL + c;
        float uv  = u[idx];
        float uuv = sigm(2.0f*(uv - S_CONST)) * uv;
        float ah  = sigm(uuv) * sigm(2.0f*(uuv - S_CONST));
        unsigned int pkd = pk2(uuv, ah);
        st[idx] = pkd;
        ahv[k] = hi2f(pkd);                      // rounded value (matches stored state)
    }
    size_t baseJI = ((size_t)b*LL + Jb)*LL + Ib;
    #pragma unroll
    for (int k = 0; k < 16; k++) {
        int xr = rg + 4*k;
        size_t idx = baseJI + (size_t)xr*LL + c;
        float uv  = u[idx];
        float uuv = sigm(2.0f*(uv - S_CONST)) * uv;
        float ah  = sigm(uuv) * sigm(2.0f*(uuv - S_CONST));
        unsigned int pkd = pk2(uuv, ah);
        if (!diag) st[idx] = pkd;                // diag: same tile, skip duplicate write
        stB[xr*SPAD + c] = hi2f(pkd);
    }
    __syncthreads();

    float buj = xJ[1*TILE + c], bgj = xJ[3*TILE + c];
    float s1j = xJ[0*TILE + c] + bgj;            // baj + bgj
    float s2j = xJ[2*TILE + c] + buj;            // bcj + buj
    float rsJ_th = 0.0f;
    #pragma unroll
    for (int k = 0; k < 16; k++) {
        int r = rg + 4*k;
        float ah_ij = ahv[k];
        float ah_ji = stB[c*SPAD + r];
        float m = xI[0*TILE + r]*buj + xI[2*TILE + r]*bgj
                + xI[1*TILE + r]*s1j + xI[3*TILE + r]*s2j;
        float a0 = 0.5f * (ah_ij*ah_ij + ah_ji*ah_ji) * m;
        stA[c*SPAD + r] = a0;                    // same-thread slot, safe
        rsJ_th += a0;
    }
    if (!diag) atomicAdd(&rsJ[c], rsJ_th);
    __syncthreads();
    { int r = tid & 63, g = tid >> 6;
      float s = 0.0f;
      #pragma unroll
      for (int q = 0; q < 16; q++) s += stA[(g*16 + q)*SPAD + r];
      atomicAdd(&rsI[r], s); }
    __syncthreads();
    if (tid < TILE) atomicAdd(&rs0[b*LL + Ib + tid], rsI[tid]);
    else if (!diag && tid < 2*TILE) atomicAdd(&rs0[b*LL + Jb + (tid - TILE)], rsJ[tid - TILE]);
}

// ---- fused step: ls/lambda recurrence (redundant per block, committed by diag block)
//      + tile update + rowsum accumulation into rs[t+1] ----
__global__ __launch_bounds__(256) void k_step(
        unsigned int* __restrict__ st, const float* __restrict__ x,
        const float* __restrict__ rs_cur, float* __restrict__ rs_next,
        const float* __restrict__ lmbd_prev, float* __restrict__ lmbd_next,
        const float* __restrict__ aW1, const float* __restrict__ ab1,
        const float* __restrict__ aW2, const float* __restrict__ ab2,
        const float* __restrict__ rW1, const float* __restrict__ rb1,
        const float* __restrict__ rW2, const float* __restrict__ rb2,
        const float* __restrict__ lw1, const float* __restrict__ lb1_,
        const float* __restrict__ lw2, const float* __restrict__ lb2_,
        float* __restrict__ out, int t) {
    __shared__ float stA[TILE * SPAD];   // uu_JI, then a_val staging
    __shared__ float stB[TILE * SPAD];   // ahat_JI, then packed JI state staging
    __shared__ float xI[4 * TILE], xJ[4 * TILE];
    __shared__ float lsI[TILE], lsJ[TILE];
    __shared__ float w[32];
    __shared__ float rsI[TILE], rsJ[TILE];

    int b = blockIdx.x / NPAIR, p = blockIdx.x % NPAIR;
    int I, J; pair_from_idx(p, I, J);
    int Ib = I * TILE, Jb = J * TILE;
    bool diag = (I == J);
    int tid = threadIdx.x, c = tid & 63, rg = tid >> 6;

    // ---- phase 1: IJ-tile packed loads into registers ----
    float uuv[16], ahv[16];
    size_t baseIJ = ((size_t)b*LL + Ib)*LL + Jb;
    #pragma unroll
    for (int k = 0; k < 16; k++) {
        unsigned int v = st[baseIJ + (size_t)(rg + 4*k)*LL + c];
        uuv[k] = lo2f(v);
        ahv[k] = hi2f(v);
    }

    // ---- phase 2: weights, x, fused lambda/ls recurrence, JI tile -> LDS ----
    if (tid < 32) {
        float v;
        if      (tid <  9) v = aW1[t*9 + tid];
        else if (tid < 12) v = ab1[t*3 + (tid-9)];
        else if (tid < 15) v = aW2[t*3 + (tid-12)];
        else if (tid < 16) v = ab2[t];
        else if (tid < 25) v = rW1[t*9 + (tid-16)];
        else if (tid < 28) v = rb1[t*3 + (tid-25)];
        else if (tid < 31) v = rW2[t*3 + (tid-28)];
        else               v = rb2[t];
        w[tid] = v;
    }
    { int row = tid >> 2, k2 = tid & 3;
      xI[k2*TILE + row] = x[((size_t)b*LL + Ib + row)*4 + k2];
      xJ[k2*TILE + row] = x[((size_t)b*LL + Jb + row)*4 + k2]; }
    if (tid < TILE) { rsI[tid] = 0.0f; rsJ[tid] = 0.0f; }
    if (tid < 128) {
        int row = (tid < 64) ? (Ib + tid) : (Jb + tid - 64);
        float rsv = rs_cur[b*LL + row];
        float lg  = fmaxf(rsv - 1.0f, 0.0f);
        float lam;
        if (t == 0) {
            lam = lg;                              // W_PEN = 1
        } else {
            float l0 = lmbd_prev[b*LL + row];
            float h0 = fmaxf(lw1[0]*l0 + lw1[1]*lg + lb1_[0], 0.0f);
            float h1 = fmaxf(lw1[2]*l0 + lw1[3]*lg + lb1_[1], 0.0f);
            float h2 = fmaxf(lw1[4]*l0 + lw1[5]*lg + lb1_[2], 0.0f);
            lam = fmaxf(lw2[0]*h0 + lw2[1]*h1 + lw2[2]*h2 + lb2_[0], 0.0f);
        }
        float lsv = lam * sigm(2.0f*(rsv - 1.0f));
        if (tid < 64) {
            lsI[tid] = lsv;
            if (diag) lmbd_next[b*LL + row] = lam;  // diag block commits lambda for tile I
        } else {
            lsJ[tid - 64] = lsv;
        }
    }
    size_t baseJI = ((size_t)b*LL + Jb)*LL + Ib;
    #pragma unroll
    for (int k = 0; k < 16; k++) {
        int xr = rg + 4*k;
        unsigned int v = st[baseJI + (size_t)xr*LL + c];
        stA[xr*SPAD + c] = lo2f(v);
        stB[xr*SPAD + c] = hi2f(v);
    }
    __syncthreads();

    // ---- phase 3: compute; stores only ----
    float buj = xJ[1*TILE + c], bgj = xJ[3*TILE + c];
    float s1j = xJ[0*TILE + c] + bgj;
    float s2j = xJ[2*TILE + c] + buj;
    size_t outBase = (((size_t)t*BB + b) * LL) * LL;
    float rsJ_th = 0.0f;
    #pragma unroll
    for (int k = 0; k < 16; k++) {
        int r = rg + 4*k;
        size_t idxIJ = baseIJ + (size_t)r*LL + c;
        float uu_ij = uuv[k];
        float ah_ij = ahv[k];
        float uu_ji = stA[c*SPAD + r];   // read before same-thread slot reuse
        float ah_ji = stB[c*SPAD + r];
        float m = xI[0*TILE + r]*buj + xI[2*TILE + r]*bgj
                + xI[1*TILE + r]*s1j + xI[3*TILE + r]*s2j;
        float gsum = -0.5f * (uu_ij + uu_ji) + lsI[r] + lsJ[c];
        float an_ij = ahnew_calc(ah_ij, ah_ij * m * gsum, uu_ij, w);
        float an_ji = ahnew_calc(ah_ji, ah_ji * m * gsum, uu_ji, w);  // diag: duplicate but correct
        float a_val = 0.5f * (an_ij*an_ij + an_ji*an_ji) * m;

        st[idxIJ] = pk_rt(uu_ij, an_ij);                              // in-place, tile owned by block
        __builtin_nontemporal_store(a_val, &out[outBase + (size_t)(Ib + r)*LL + (Jb + c)]);

        stA[c*SPAD + r] = a_val;                                      // stage for reduce + JI out
        stB[c*SPAD + r] = __uint_as_float(pk_rt(uu_ji, an_ji));       // stage packed JI state
        rsJ_th += a_val;                                              // a[Jb+c][Ib+r] == a_val
    }
    if (!diag) atomicAdd(&rsJ[c], rsJ_th);
    __syncthreads();
    if (!diag) {
        #pragma unroll
        for (int k = 0; k < 16; k++) {
            int xr = rg + 4*k;
            st[baseJI + (size_t)xr*LL + c] = __float_as_uint(stB[xr*SPAD + c]);
            __builtin_nontemporal_store(stA[xr*SPAD + c],
                                        &out[outBase + (size_t)(Jb + xr)*LL + (Ib + c)]);
        }
    }
    if (t != TT-1) {                                  // uniform branch; barrier inside is safe
        int r = tid & 63, g = tid >> 6;
        float s = 0.0f;
        #pragma unroll
        for (int q = 0; q < 16; q++) s += stA[(g*16 + q)*SPAD + r];
        atomicAdd(&rsI[r], s);
        __syncthreads();
        if (tid < TILE) atomicAdd(&rs_next[b*LL + Ib + tid], rsI[tid]);
        else if (!diag && tid < 2*TILE) atomicAdd(&rs_next[b*LL + Jb + (tid - TILE)], rsJ[tid - TILE]);
    }
}

extern "C" void kernel_launch(void* const* d_in, const int* in_sizes, int n_in,
                              void* d_out, int out_size, void* d_ws, size_t ws_size,
                              hipStream_t stream) {
    const float* u   = (const float*)d_in[0];
    const float* x   = (const float*)d_in[1];
    const float* aW1 = (const float*)d_in[3];
    const float* ab1 = (const float*)d_in[4];
    const float* aW2 = (const float*)d_in[5];
    const float* ab2 = (const float*)d_in[6];
    const float* rW1 = (const float*)d_in[7];
    const float* rb1 = (const float*)d_in[8];
    const float* rW2 = (const float*)d_in[9];
    const float* rb2 = (const float*)d_in[10];
    const float* lW1 = (const float*)d_in[11];
    const float* lb1 = (const float*)d_in[12];
    const float* lW2 = (const float*)d_in[13];
    const float* lb2 = (const float*)d_in[14];
    float* out = (float*)d_out;

    char* ws = (char*)d_ws;
    size_t stBytes = (size_t)BB * LL * LL * sizeof(unsigned int);
    unsigned int* st = (unsigned int*)ws;
    float* rs    = (float*)(ws + stBytes);          // TT rowsum buffers, rs + t*BB*LL
    float* lmbdA = rs + (size_t)TT * BB * LL;
    float* lmbdB = lmbdA + BB * LL;

    hipMemsetAsync(rs, 0, (size_t)TT * BB * LL * sizeof(float), stream);
    hipLaunchKernelGGL(k_init, dim3(BB*NPAIR), dim3(256), 0, stream, u, x, st, rs);

    for (int t = 0; t < TT; ++t) {
        float* lnext = (t & 1) ? lmbdB : lmbdA;
        float* lprev = (t & 1) ? lmbdA : lmbdB;     // t=0: unused (guarded)
        const float* rs_cur = rs + (size_t)t * BB * LL;
        float* rs_nextp = (t < TT-1) ? (rs + (size_t)(t+1) * BB * LL) : rs;  // unused at last t
        int toff = (t > 0) ? (t - 1) : 0;           // lambda-MLP weights index (unused at t=0)
        hipLaunchKernelGGL(k_step, dim3(BB*NPAIR), dim3(256), 0, stream,
                           st, x, rs_cur, rs_nextp, lprev, lnext,
                           aW1, ab1, aW2, ab2, rW1, rb1, rW2, rb2,
                           lW1 + toff*6, lb1 + toff*3, lW2 + toff*3, lb2 + toff,
                           out, t);
    }
}